// Round 13
// baseline (92.663 us; speedup 1.0000x reference)
//
#include <hip/hip_runtime.h>
#include <stdint.h>

#define M_TOK 512
#define N_OUT 11008
#define K_IN  4096
#define BM 128
#define BN 128
#define BK 64
#define KSPLIT_LEN 2048

typedef int i32x4 __attribute__((ext_vector_type(4)));

// =============================================================================
// Pre-pass: per-token-row int8 quantization of x (absmax/127), emitted in
// MFMA-FRAGMENT layout: chunk (kc16 = k>>4, gm = m>>4) stored at
//   x8f[((kc16*32) + gm)*256 + (m&15)*16 + (k&15)]
// A-frag load = fully coalesced dwordx4 from the L2-resident 2MB buffer.
// Verified rounds 11-12 (absmax 4.125).
// =============================================================================
__global__ void xquant_kernel(const float* __restrict__ x, int8_t* __restrict__ x8f,
                              float* __restrict__ sx) {
  const int row = blockIdx.x * 4 + (threadIdx.x >> 6);
  const int lane = threadIdx.x & 63;
  const float4* xr = (const float4*)(x + (size_t)row * K_IN);

  float4 v[16];
  float m = 0.f;
#pragma unroll
  for (int j = 0; j < 16; ++j) {
    v[j] = xr[lane * 16 + j];
    m = fmaxf(m, fmaxf(fmaxf(fabsf(v[j].x), fabsf(v[j].y)),
                       fmaxf(fabsf(v[j].z), fabsf(v[j].w))));
  }
#pragma unroll
  for (int o = 32; o; o >>= 1) m = fmaxf(m, __shfl_xor(m, o));

  const float inv = 127.0f / m;
  if (lane == 0) sx[row] = m / 127.0f;

  uint32_t d[16];
#pragma unroll
  for (int j = 0; j < 16; ++j) {
    int a = __float2int_rn(v[j].x * inv);
    int b = __float2int_rn(v[j].y * inv);
    int c = __float2int_rn(v[j].z * inv);
    int e = __float2int_rn(v[j].w * inv);
    d[j] = (a & 0xFF) | ((b & 0xFF) << 8) | ((c & 0xFF) << 16) | (e << 24);
  }
  const int gm = row >> 4, mr = row & 15;
#pragma unroll
  for (int q = 0; q < 4; ++q) {
    const int kc16 = lane * 4 + q;
    *(uint4*)&x8f[(size_t)(kc16 * 32 + gm) * 256 + mr * 16] =
        make_uint4(d[4 * q], d[4 * q + 1], d[4 * q + 2], d[4 * q + 3]);
  }
}

// ---- reduce: out += part ----------------------------------------------------
__global__ void reduce_kernel(float4* __restrict__ out, const float4* __restrict__ p, int n4) {
  int i = blockIdx.x * blockDim.x + threadIdx.x;
  int stride = gridDim.x * blockDim.x;
  for (; i < n4; i += stride) {
    float4 a = out[i];
    float4 b = p[i];
    a.x += b.x; a.y += b.y; a.z += b.z; a.w += b.w;
    out[i] = a;
  }
}

// =============================================================================
// int8 GEMM, BM128 x BN128 x BK64, split-K=2, grid 688.
// TWO k-tiles per barrier span (T3 essence): one lgkm-only raw barrier per
// span, 32 MFMA/span/wave (vs 16 in round 12), 16 spans per block.
//   Bs[buf][sub]: 2 buffers x 2 sub-tiles x 8KB = 32KB LDS.
//   B: reg-staged in TWO NAMED 8-arrays brE/brO (static indexing, rule #20).
//      Issue at span s -> LDS-write at span s+1 start -> ~1 full span (~700cyc)
//      of load cover. Barriers never drain vmcnt (A/B loads fly across).
//   A: fragment regs direct from L2-resident x8f (no LDS, no vmcnt at bar).
// =============================================================================
template <bool SPLIT>
__global__ __launch_bounds__(256, 2)
void qgemm_i8(const int8_t* __restrict__ x8f, const float* __restrict__ sx,
              const int* __restrict__ qw, const float* __restrict__ scale,
              const float* __restrict__ bias, float* __restrict__ out,
              float* __restrict__ part) {
  __shared__ __align__(16) int8_t Bs[2][2][BN * BK];  // [buf][sub] 8KB each

  const int tid = threadIdx.x;
  const int lane = tid & 63;
  const int wid = tid >> 6;
  const int wm = wid >> 1, wn = wid & 1;
  const int kc = lane >> 4;

  int nt, mt, ks;
  if constexpr (SPLIT) {
    const int xcd = blockIdx.x & 7;
    const int g = xcd * 86 + (blockIdx.x >> 3);
    nt = g >> 3;
    const int r = g & 7;
    ks = r >> 2;
    mt = r & 3;
  } else {
    const int xcd = blockIdx.x & 7;
    const int g = xcd * 43 + (blockIdx.x >> 3);
    nt = g >> 2;
    mt = g & 3;
    ks = 0;
  }
  const int bm0 = mt * BM, bn0 = nt * BN;
  const int kbase = SPLIT ? ks * KSPLIT_LEN : 0;
  const int NSPAN = (SPLIT ? KSPLIT_LEN : K_IN) / (2 * BK);  // 16 or 32

  const int gmbase = (bm0 >> 4) + wm * 4;

  i32x4 acc[4][4] = {};
  i32x4 aE[4], aO[4];    // A frags for the span's two sub-tiles
  int4 brE[8], brO[8];   // B staging: named per sub-tile (static, rule #20)

  const int brow = tid >> 2;
  const int bq = tid & 3;

#define LGKM_BAR() asm volatile("s_waitcnt lgkmcnt(0)\ns_barrier" ::: "memory")

#define A_FRAG_LOAD(DST, kb)                                                     \
  {                                                                              \
    const int kc16 = ((kb) >> 4) + kc;                                           \
    _Pragma("unroll") for (int mi = 0; mi < 4; ++mi) {                           \
      DST[mi] = *(const i32x4*)&x8f[(size_t)(kc16 * 32 + gmbase + mi) * 256 +    \
                                    (lane & 15) * 16];                           \
    }                                                                            \
  }

#define B_ISSUE(REG, kb)                                                         \
  {                                                                              \
    _Pragma("unroll") for (int j = 0; j < 2; ++j) {                              \
      const int row = brow + j * 64;                                             \
      const int4* bp = (const int4*)(qw + (size_t)(bn0 + row) * K_IN + (kb) + bq * 16); \
      _Pragma("unroll") for (int k = 0; k < 4; ++k) REG[4 * j + k] = bp[k];      \
    }                                                                            \
  }

#define B_WRITE(REG, BI, SUB)                                                    \
  {                                                                              \
    _Pragma("unroll") for (int j = 0; j < 2; ++j) {                              \
      const int row = brow + j * 64;                                             \
      uint32_t d[4];                                                             \
      _Pragma("unroll") for (int k = 0; k < 4; ++k) {                            \
        int4 w = REG[4 * j + k];                                                 \
        uint32_t lo = __builtin_amdgcn_perm((uint32_t)w.y, (uint32_t)w.x, 0x0C0C0400u); \
        uint32_t hi = __builtin_amdgcn_perm((uint32_t)w.w, (uint32_t)w.z, 0x04000C0Cu); \
        d[k] = lo | hi;                                                          \
      }                                                                          \
      const int ch = bq ^ ((row >> 1) & 3);                                      \
      *(uint4*)&Bs[BI][SUB][row * 64 + ch * 16] = make_uint4(d[0], d[1], d[2], d[3]); \
    }                                                                            \
  }

#define COMPUTE(AR, BI, SUB)                                                     \
  {                                                                              \
    i32x4 b[4];                                                                  \
    _Pragma("unroll") for (int ni = 0; ni < 4; ++ni) {                           \
      const int row = wn * 64 + ni * 16 + (lane & 15);                           \
      const int ch = kc ^ ((row >> 1) & 3);                                      \
      b[ni] = *(const i32x4*)&Bs[BI][SUB][row * 64 + ch * 16];                   \
    }                                                                            \
    __builtin_amdgcn_s_setprio(1);                                               \
    _Pragma("unroll") for (int mi = 0; mi < 4; ++mi)                             \
      _Pragma("unroll") for (int ni = 0; ni < 4; ++ni)                           \
        acc[mi][ni] = __builtin_amdgcn_mfma_i32_16x16x64_i8(AR[mi], b[ni],       \
                                                            acc[mi][ni], 0, 0, 0); \
    __builtin_amdgcn_s_setprio(0);                                               \
  }

  // ---- prologue: tiles 0,1 staged into Bs[0]; tiles 2,3 in flight ----
  B_ISSUE(brE, kbase);
  B_ISSUE(brO, kbase + BK);
  B_WRITE(brE, 0, 0);
  B_WRITE(brO, 0, 1);
  B_ISSUE(brE, kbase + 2 * BK);
  B_ISSUE(brO, kbase + 3 * BK);

#pragma unroll 1
  for (int s = 0; s < NSPAN; ++s) {
    const int cur = s & 1, nxt = cur ^ 1;
    const int k0 = kbase + 2 * s * BK;

    LGKM_BAR();  // Bs[cur] writes visible; WAR: all waves done with Bs[nxt]

    // A frags for this span (L2-hot; aO's wait covered by COMPUTE(aE))
    A_FRAG_LOAD(aE, k0);
    A_FRAG_LOAD(aO, k0 + BK);

    // stage tiles 2s+2, 2s+3 into Bs[nxt] (loads issued one span ago)
    if (s + 1 < NSPAN) {
      B_WRITE(brE, nxt, 0);
      B_WRITE(brO, nxt, 1);
    }
    // issue tiles 2s+4, 2s+5 (consumed by B_WRITE at span s+1)
    if (s + 2 < NSPAN) {
      B_ISSUE(brE, k0 + 4 * BK);
      B_ISSUE(brO, k0 + 5 * BK);
    }

    // ---- 32 MFMA on Bs[cur] ----
    COMPUTE(aE, cur, 0);
    COMPUTE(aO, cur, 1);
  }

  // ---- epilogue ----
  float* dst = out;
  float badd = 1.0f;
  if constexpr (SPLIT) {
    if (ks == 1) { dst = part; badd = 0.0f; }
  }
  float sxr[4][4];
#pragma unroll
  for (int mi = 0; mi < 4; ++mi)
#pragma unroll
    for (int r = 0; r < 4; ++r)
      sxr[mi][r] = sx[bm0 + wm * 64 + mi * 16 + (lane >> 4) * 4 + r];

#pragma unroll
  for (int ni = 0; ni < 4; ++ni) {
    const int col = bn0 + wn * 64 + ni * 16 + (lane & 15);
    const float sw = scale[col];
    const float bi = bias[col] * badd;
#pragma unroll
    for (int mi = 0; mi < 4; ++mi) {
      const int rowb = bm0 + wm * 64 + mi * 16 + (lane >> 4) * 4;
#pragma unroll
      for (int r = 0; r < 4; ++r) {
        dst[(size_t)(rowb + r) * N_OUT + col] = (float)acc[mi][ni][r] * sxr[mi][r] * sw + bi;
      }
    }
  }
#undef LGKM_BAR
#undef A_FRAG_LOAD
#undef B_ISSUE
#undef B_WRITE
#undef COMPUTE
}

// ---- naive fallback (ws too small; not expected to run) ---------------------
__global__ void qgemm_naive(const float* __restrict__ x, const int* __restrict__ qw,
                            const float* __restrict__ scale, const float* __restrict__ bias,
                            float* __restrict__ out) {
  int o = blockIdx.x * blockDim.x + threadIdx.x;
  if (o >= M_TOK * N_OUT) return;
  int row = o / N_OUT, col = o % N_OUT;
  const float* xr = x + (size_t)row * K_IN;
  const int* wr = qw + (size_t)col * K_IN;
  float acc = 0.f;
  for (int k = 0; k < K_IN; ++k) acc += xr[k] * (float)wr[k];
  out[o] = acc * scale[col] + bias[col];
}

// ---- launch ------------------------------------------------------------------
extern "C" void kernel_launch(void* const* d_in, const int* in_sizes, int n_in,
                              void* d_out, int out_size, void* d_ws, size_t ws_size,
                              hipStream_t stream) {
  const float* x = (const float*)d_in[0];
  const int* qw = (const int*)d_in[1];
  const float* scale = (const float*)d_in[2];
  const float* bias = (const float*)d_in[3];
  float* out = (float*)d_out;

  const size_t sx_bytes = 4096;                         // 512 floats, padded
  const size_t x8_bytes = (size_t)M_TOK * K_IN;         // 2 MB
  const size_t part_bytes = (size_t)M_TOK * N_OUT * 4;  // 22.5 MB
  const int n4 = M_TOK * N_OUT / 4;

  if (ws_size >= sx_bytes + x8_bytes + part_bytes) {
    float* sx = (float*)d_ws;
    int8_t* x8f = (int8_t*)((char*)d_ws + sx_bytes);
    float* part = (float*)((char*)d_ws + sx_bytes + x8_bytes);
    xquant_kernel<<<dim3(M_TOK / 4), dim3(256), 0, stream>>>(x, x8f, sx);
    qgemm_i8<true><<<dim3(688), dim3(256), 0, stream>>>(x8f, sx, qw, scale, bias, out, part);
    reduce_kernel<<<dim3(2048), dim3(256), 0, stream>>>((float4*)out, (const float4*)part, n4);
  } else if (ws_size >= sx_bytes + x8_bytes) {
    float* sx = (float*)d_ws;
    int8_t* x8f = (int8_t*)((char*)d_ws + sx_bytes);
    xquant_kernel<<<dim3(M_TOK / 4), dim3(256), 0, stream>>>(x, x8f, sx);
    qgemm_i8<false><<<dim3(344), dim3(256), 0, stream>>>(x8f, sx, qw, scale, bias, out, nullptr);
  } else {
    qgemm_naive<<<dim3((M_TOK * N_OUT + 255) / 256), dim3(256), 0, stream>>>(
        x, qw, scale, bias, out);
  }
}